// Round 18
// baseline (723.569 us; speedup 1.0000x reference)
//
#include <hip/hip_runtime.h>

#define NROWS 50000
#define NFEAT 512
#define NEDGE 1600000
#define SLOPE 0.01f

typedef unsigned short u16;
typedef __attribute__((ext_vector_type(8))) short short8;
typedef __attribute__((ext_vector_type(4))) float f32x4;
typedef __attribute__((ext_vector_type(4))) int i32x4;
typedef __attribute__((ext_vector_type(8))) unsigned short u16x8;

__device__ __forceinline__ u16 f2bf(float f) {
  unsigned u = __float_as_uint(f);
  u += 0x7fffu + ((u >> 16) & 1u);
  return (u16)(u >> 16);
}
__device__ __forceinline__ float lrelu(float v) { return v >= 0.f ? v : SLOPE * v; }

__device__ __forceinline__ void gload_lds16(const u16* g, u16* l) {
  __builtin_amdgcn_global_load_lds((const __attribute__((address_space(1))) void*)g,
                                   (__attribute__((address_space(3))) void*)l, 16, 0, 0);
}

// ---- fused prep: xd = bf16(x*mask), wb = bf16(W), counts = row histogram,
//      + last-block-done inline scan (counts -> offs), no separate scan launch ----
__global__ __launch_bounds__(256) void prep_kernel(
    const float* __restrict__ x, const float* __restrict__ m, u16* __restrict__ xd,
    const float* __restrict__ w, u16* __restrict__ wb, const int* __restrict__ rows,
    int* __restrict__ counts, int* __restrict__ done, int* __restrict__ offs) {
  const int stride = gridDim.x * blockDim.x;
  const int tid0 = blockIdx.x * blockDim.x + threadIdx.x;
  for (int i = tid0; i < (NROWS * NFEAT) / 8; i += stride) {
    size_t b = (size_t)i * 2;
    f32x4 a0 = __builtin_nontemporal_load(&((const f32x4*)x)[b]);
    f32x4 a1 = __builtin_nontemporal_load(&((const f32x4*)x)[b + 1]);
    f32x4 m0 = __builtin_nontemporal_load(&((const f32x4*)m)[b]);
    f32x4 m1 = __builtin_nontemporal_load(&((const f32x4*)m)[b + 1]);
    u16x8 o;
    o[0] = f2bf(a0[0] * m0[0]); o[1] = f2bf(a0[1] * m0[1]);
    o[2] = f2bf(a0[2] * m0[2]); o[3] = f2bf(a0[3] * m0[3]);
    o[4] = f2bf(a1[0] * m1[0]); o[5] = f2bf(a1[1] * m1[1]);
    o[6] = f2bf(a1[2] * m1[2]); o[7] = f2bf(a1[3] * m1[3]);
    *(u16x8*)(xd + (size_t)i * 8) = o;
  }
  for (int i = tid0; i < (NFEAT * NFEAT) / 8; i += stride) {
    size_t b = (size_t)i * 2;
    f32x4 a0 = __builtin_nontemporal_load(&((const f32x4*)w)[b]);
    f32x4 a1 = __builtin_nontemporal_load(&((const f32x4*)w)[b + 1]);
    u16x8 o;
    o[0] = f2bf(a0[0]); o[1] = f2bf(a0[1]); o[2] = f2bf(a0[2]); o[3] = f2bf(a0[3]);
    o[4] = f2bf(a1[0]); o[5] = f2bf(a1[1]); o[6] = f2bf(a1[2]); o[7] = f2bf(a1[3]);
    *(u16x8*)(wb + (size_t)i * 8) = o;
  }
  for (int i = tid0; i < NEDGE / 4; i += stride) {
    i32x4 r4 = __builtin_nontemporal_load(&((const i32x4*)rows)[i]);
    atomicAdd(&counts[r4[0]], 1);
    atomicAdd(&counts[r4[1]], 1);
    atomicAdd(&counts[r4[2]], 1);
    atomicAdd(&counts[r4[3]], 1);
  }

  // ---- last-block-done: the final block to finish performs the scan ----
  __shared__ int isLast;
  __threadfence();  // release this block's count atomics
  __syncthreads();
  if (threadIdx.x == 0) isLast = (atomicAdd(done, 1) == (int)gridDim.x - 1);
  __syncthreads();
  if (!isLast) return;
  __threadfence();  // acquire: all counts visible

  // scan with 256 threads: 196 rows/thread (int4 granular; thread 255 gets 20)
  __shared__ int wpre[5];
  const int t = threadIdx.x;
  const int lane = t & 63, wv = t >> 6;  // 4 waves
  const int beg = t * 196;
  const int end = (beg + 196 < NROWS) ? beg + 196 : NROWS;
  i32x4 c4[49];
  int s = 0;
  const int ng4 = (end > beg) ? (end - beg) >> 2 : 0;
#pragma unroll 8
  for (int g = 0; g < ng4; ++g) {
    c4[g] = ((const i32x4*)counts)[(beg >> 2) + g];
    s += c4[g][0] + c4[g][1] + c4[g][2] + c4[g][3];
  }
  int inc = s;
#pragma unroll
  for (int d = 1; d < 64; d <<= 1) {
    int u = __shfl_up(inc, d);
    if (lane >= d) inc += u;
  }
  if (lane == 63) wpre[wv + 1] = inc;
  __syncthreads();
  if (t == 0) {
    wpre[0] = 0;
    for (int i = 1; i <= 4; ++i) wpre[i] += wpre[i - 1];
    offs[NROWS] = NEDGE;
  }
  __syncthreads();
  int run = wpre[wv] + inc - s;
#pragma unroll 8
  for (int g = 0; g < ng4; ++g) {
    i32x4 o;
    o[0] = run; run += c4[g][0];
    o[1] = run; run += c4[g][1];
    o[2] = run; run += c4[g][2];
    o[3] = run; run += c4[g][3];
    ((i32x4*)offs)[(beg >> 2) + g] = o;
  }
}

// ---- hybrid: bid<1564 -> gemm (long pole, starts first); else -> scatter ----
#define GEMM_BLOCKS 1564
__global__ __launch_bounds__(256) void hybrid_kernel(
    const float* __restrict__ vals, const int* __restrict__ rows,
    const int* __restrict__ cols, const int* __restrict__ offs,
    int* __restrict__ cursor, unsigned* __restrict__ svc,
    const u16* __restrict__ xd, const u16* __restrict__ wb,
    unsigned char* __restrict__ hq, float* __restrict__ scaleg) {
  __shared__ __align__(16) u16 lA[128 * 64];  // 16 KB (gemm path only)
  __shared__ float wmax[2][128];
  __shared__ float rinv[128];
  const int tid = threadIdx.x;

  if (blockIdx.x >= GEMM_BLOCKS) {
    // ================= scatter path =================
    int e0 = ((blockIdx.x - GEMM_BLOCKS) * 256 + tid) * 4;
    if (e0 >= NEDGE) return;
    i32x4 r4 = __builtin_nontemporal_load((const i32x4*)(rows + e0));
    i32x4 c4 = __builtin_nontemporal_load((const i32x4*)(cols + e0));
    f32x4 v4 = __builtin_nontemporal_load((const f32x4*)(vals + e0));
#pragma unroll
    for (int j = 0; j < 4; ++j) {
      int p = offs[r4[j]] + atomicAdd(&cursor[r4[j]], 1);
      svc[p] = ((unsigned)c4[j] << 16) | (unsigned)f2bf(v4[j]);
    }
    return;
  }

  // ================= gemm path =================
  const int lane = tid & 63;
  const int wid = tid >> 6;
  const int wm = wid >> 1, wn = wid & 1;
  // bijective XCD swizzle over nwg = 1564 (q=195, r=4)
  const int bx0 = blockIdx.x;
  const int xcd = bx0 & 7, idx = bx0 >> 3;
  const int wg = (xcd < 4 ? xcd * 196 : 784 + (xcd - 4) * 195) + idx;
  const int tm = wg >> 2;
  const int tn = wg & 3;
  const long rowBase = (long)tm * 128;

  f32x4 acc[4][4] = {};

  const int sl8 = lane >> 3;                 // row within 8-row staging call
  const int scol = ((lane & 7) ^ sl8) * 8;   // pre-swizzled global col (u16 units)
  const int rsel = lane & 15, kgrp = (lane >> 4) * 8;
  const u16* bbase = wb + ((long)(tn * 128 + wn * 64 + rsel)) * 512 + kgrp;

  for (int k0 = 0; k0 < 512; k0 += 64) {
    __syncthreads();
#pragma unroll
    for (int c = 0; c < 4; ++c) {
      int rbase = wid * 32 + c * 8;
      long gr = rowBase + rbase + sl8;
      if (gr > NROWS - 1) gr = NROWS - 1;
      gload_lds16(xd + gr * 512 + k0 + scol, lA + rbase * 64);
    }
    // B fragments direct from global (wb is 512 KB, L2-resident)
    short8 b[4][2];
#pragma unroll
    for (int n = 0; n < 4; ++n) {
#pragma unroll
      for (int kk = 0; kk < 2; ++kk)
        b[n][kk] = *(const short8*)(bbase + (long)n * 16 * 512 + k0 + kk * 32);
    }
    __syncthreads();
    short8 a[4][2];
#pragma unroll
    for (int m = 0; m < 4; ++m) {
      int ar = wm * 64 + m * 16 + rsel;
      const u16* base = lA + ar * 64;
      int sw = (ar & 7) << 3;
      a[m][0] = *(const short8*)(base + (kgrp ^ sw));
      a[m][1] = *(const short8*)(base + ((32 + kgrp) ^ sw));
    }
#pragma unroll
    for (int kk = 0; kk < 2; ++kk)
#pragma unroll
      for (int m = 0; m < 4; ++m)
#pragma unroll
        for (int n = 0; n < 4; ++n)
          acc[m][n] = __builtin_amdgcn_mfma_f32_16x16x32_bf16(a[m][kk], b[n][kk], acc[m][n], 0, 0, 0);
  }

  // ---- epilogue: per-row max -> scale, int8 quantize, LDS byte-transpose ----
  const int crow = (lane >> 4) * 4;
  const int ccol = lane & 15;

  float pm[4][4];
#pragma unroll
  for (int m = 0; m < 4; ++m)
#pragma unroll
    for (int r2 = 0; r2 < 4; ++r2) {
      float mx = 0.f;
#pragma unroll
      for (int n = 0; n < 4; ++n) mx = fmaxf(mx, fabsf(lrelu(acc[m][n][r2])));
      pm[m][r2] = mx;
    }
#pragma unroll
  for (int d = 1; d < 16; d <<= 1)
#pragma unroll
    for (int m = 0; m < 4; ++m)
#pragma unroll
      for (int r2 = 0; r2 < 4; ++r2) pm[m][r2] = fmaxf(pm[m][r2], __shfl_xor(pm[m][r2], d));
  if ((lane & 15) == 0) {
#pragma unroll
    for (int m = 0; m < 4; ++m)
#pragma unroll
      for (int r2 = 0; r2 < 4; ++r2) wmax[wn][wm * 64 + m * 16 + crow + r2] = pm[m][r2];
  }
  __syncthreads();  // wmax ready AND all waves done reading lA
  if (tid < 128) {
    float rm = fmaxf(wmax[0][tid], wmax[1][tid]);
    float s = rm > 0.f ? rm * (1.f / 127.f) : 1.f;
    rinv[tid] = rm > 0.f ? 127.f / rm : 0.f;
    long gr = rowBase + tid;
    if (gr < NROWS) scaleg[gr * 4 + tn] = s;
  }
  __syncthreads();

  unsigned char* lT = (unsigned char*)lA;  // 128 x 128 int8 tile (16 KB)
#pragma unroll
  for (int m = 0; m < 4; ++m) {
    int row0 = wm * 64 + m * 16 + crow;
    float ri0 = rinv[row0], ri1 = rinv[row0 + 1], ri2 = rinv[row0 + 2], ri3 = rinv[row0 + 3];
#pragma unroll
    for (int n = 0; n < 4; ++n) {
      int col = wn * 64 + n * 16 + ccol;
      float q0 = rintf(lrelu(acc[m][n][0]) * ri0);
      float q1 = rintf(lrelu(acc[m][n][1]) * ri1);
      float q2 = rintf(lrelu(acc[m][n][2]) * ri2);
      float q3 = rintf(lrelu(acc[m][n][3]) * ri3);
      int i0 = min(127, max(-127, (int)q0));
      int i1 = min(127, max(-127, (int)q1));
      int i2 = min(127, max(-127, (int)q2));
      int i3 = min(127, max(-127, (int)q3));
      unsigned pk = (i0 & 0xff) | ((i1 & 0xff) << 8) | ((i2 & 0xff) << 16) | ((i3 & 0xff) << 24);
#pragma unroll
      for (int r2 = 0; r2 < 4; ++r2) {
        int row = row0 + r2;
        lT[row * 128 + (col ^ ((row & 7) << 4))] = (unsigned char)(pk >> (8 * r2));
      }
    }
  }
  __syncthreads();
  {
    const int row = tid >> 1, seg = tid & 1;
    long gr = rowBase + row;
    if (gr < NROWS) {
      unsigned char* dst = hq + gr * 512 + tn * 128;
#pragma unroll
      for (int j = 0; j < 4; ++j) {
        int s = seg * 4 + j;
        i32x4 vv = *(const i32x4*)(lT + row * 128 + ((s ^ (row & 7)) << 4));
        *(i32x4*)(dst + s * 16) = vv;
      }
    }
  }
}

// ---- aggregate: one WAVE per row, 2 edges/wave (32 lanes each), 16B gathers ----
__global__ __launch_bounds__(256) void aggregate_kernel(const unsigned char* __restrict__ hq,
                                                        const float* __restrict__ scaleg,
                                                        const unsigned* __restrict__ svc,
                                                        const int* __restrict__ offs,
                                                        float* __restrict__ out) {
  const int lane = threadIdx.x & 63;
  const int wid = threadIdx.x >> 6;
  const int r = blockIdx.x * 4 + wid;
  if (r >= NROWS) return;
  const int beg = offs[r], end = offs[r + 1];
  const int half = lane >> 5, sub = lane & 31;
  const int grp = sub >> 3;
  float a[16] = {};
  const unsigned char* hp = hq + sub * 16;
  unsigned cb[4], nb[4];
  const int n = end - beg;
  const int ng = n >> 3;
  if (ng > 0) {
#pragma unroll
    for (int k = 0; k < 4; ++k) cb[k] = svc[beg + 2 * k + half];
  }
  for (int g = 0; g < ng; ++g) {
    if (g + 1 < ng) {
#pragma unroll
      for (int k = 0; k < 4; ++k) nb[k] = svc[beg + (g + 1) * 8 + 2 * k + half];
    }
#pragma unroll
    for (int k = 0; k < 4; ++k) {
      float v = __uint_as_float(cb[k] << 16);
      size_t c = (size_t)(cb[k] >> 16);
      float vs = v * scaleg[c * 4 + grp];
      i32x4 q = *(const i32x4*)(hp + c * 512);
#pragma unroll
      for (int j = 0; j < 4; ++j) {
        unsigned qq = (unsigned)q[j];
        a[4 * j + 0] += vs * (float)(signed char)(qq);
        a[4 * j + 1] += vs * (float)(signed char)(qq >> 8);
        a[4 * j + 2] += vs * (float)(signed char)(qq >> 16);
        a[4 * j + 3] += vs * (float)(signed char)(qq >> 24);
      }
    }
    if (g + 1 < ng) {
#pragma unroll
      for (int k = 0; k < 4; ++k) cb[k] = nb[k];
    }
  }
  int e = beg + ng * 8;
  for (; e + 1 < end; e += 2) {
    unsigned u = svc[e + half];
    float v = __uint_as_float(u << 16);
    size_t c = (size_t)(u >> 16);
    float vs = v * scaleg[c * 4 + grp];
    i32x4 q = *(const i32x4*)(hp + c * 512);
#pragma unroll
    for (int j = 0; j < 4; ++j) {
      unsigned qq = (unsigned)q[j];
      a[4 * j + 0] += vs * (float)(signed char)(qq);
      a[4 * j + 1] += vs * (float)(signed char)(qq >> 8);
      a[4 * j + 2] += vs * (float)(signed char)(qq >> 16);
      a[4 * j + 3] += vs * (float)(signed char)(qq >> 24);
    }
  }
  if (e < end) {
    unsigned u = svc[e];
    float v = __uint_as_float(u << 16);
    size_t c = (size_t)(u >> 16);
    float vs = half ? 0.f : v * scaleg[c * 4 + grp];
    i32x4 q = *(const i32x4*)(hp + c * 512);
#pragma unroll
    for (int j = 0; j < 4; ++j) {
      unsigned qq = (unsigned)q[j];
      a[4 * j + 0] += vs * (float)(signed char)(qq);
      a[4 * j + 1] += vs * (float)(signed char)(qq >> 8);
      a[4 * j + 2] += vs * (float)(signed char)(qq >> 16);
      a[4 * j + 3] += vs * (float)(signed char)(qq >> 24);
    }
  }
#pragma unroll
  for (int j = 0; j < 16; ++j) a[j] += __shfl_xor(a[j], 32);
  if (half == 0) {
    float* op = out + (size_t)r * NFEAT + sub * 16;
#pragma unroll
    for (int j = 0; j < 4; ++j) {
      f32x4 o;
      o[0] = lrelu(a[4 * j + 0]);
      o[1] = lrelu(a[4 * j + 1]);
      o[2] = lrelu(a[4 * j + 2]);
      o[3] = lrelu(a[4 * j + 3]);
      *(f32x4*)(op + 4 * j) = o;
    }
  }
}

extern "C" void kernel_launch(void* const* d_in, const int* in_sizes, int n_in,
                              void* d_out, int out_size, void* d_ws, size_t ws_size,
                              hipStream_t stream) {
  const float* x = (const float*)d_in[0];
  const float* W = (const float*)d_in[1];
  const float* mask = (const float*)d_in[2];
  const float* vals = (const float*)d_in[3];
  const int* rows = (const int*)d_in[4];
  const int* cols = (const int*)d_in[5];
  float* out = (float*)d_out;
  char* ws = (char*)d_ws;

  const size_t o_xd = 0;                       // 51,200,000 (bf16 x*mask)
  const size_t o_hq = o_xd + 51200000;         // 25,600,000 (int8 h)
  const size_t o_wb = o_hq + 25600000;         // 524,288
  const size_t o_scale = o_wb + 524288;        // 800,000 (f32 scale[row][4])
  const size_t o_counts = o_scale + 800000;    // 200,000
  const size_t o_cursor = o_counts + 200000;   // 200,000
  const size_t o_done = o_cursor + 200000;     // 64 (int + pad)
  const size_t o_offs = o_done + 64;           // 200,064
  const size_t o_svc = o_offs + 200064;        // 6,400,000 (u32 packed col|bf16val)

  u16* xd = (u16*)(ws + o_xd);
  unsigned char* hq = (unsigned char*)(ws + o_hq);
  u16* wb = (u16*)(ws + o_wb);
  float* scaleg = (float*)(ws + o_scale);
  int* counts = (int*)(ws + o_counts);
  int* cursor = (int*)(ws + o_cursor);
  int* done = (int*)(ws + o_done);
  int* offs = (int*)(ws + o_offs);
  unsigned* svc = (unsigned*)(ws + o_svc);

  hipMemsetAsync(counts, 0, 400064, stream);  // counts + cursor + done

  prep_kernel<<<2048, 256, 0, stream>>>(x, mask, xd, W, wb, rows, counts, done, offs);
  hybrid_kernel<<<GEMM_BLOCKS + 1563, 256, 0, stream>>>(vals, rows, cols, offs, cursor,
                                                        svc, xd, wb, hq, scaleg);
  aggregate_kernel<<<12500, 256, 0, stream>>>(hq, scaleg, svc, offs, out);
}

// Round 19
// 721.640 us; speedup vs baseline: 1.0027x; 1.0027x over previous
//
#include <hip/hip_runtime.h>

#define NROWS 50000
#define NFEAT 512
#define NEDGE 1600000
#define SLOPE 0.01f

typedef unsigned short u16;
typedef __attribute__((ext_vector_type(8))) short short8;
typedef __attribute__((ext_vector_type(4))) float f32x4;
typedef __attribute__((ext_vector_type(4))) int i32x4;
typedef __attribute__((ext_vector_type(8))) unsigned short u16x8;

__device__ __forceinline__ u16 f2bf(float f) {
  unsigned u = __float_as_uint(f);
  u += 0x7fffu + ((u >> 16) & 1u);
  return (u16)(u >> 16);
}
__device__ __forceinline__ float lrelu(float v) { return v >= 0.f ? v : SLOPE * v; }

__device__ __forceinline__ void gload_lds16(const u16* g, u16* l) {
  __builtin_amdgcn_global_load_lds((const __attribute__((address_space(1))) void*)g,
                                   (__attribute__((address_space(3))) void*)l, 16, 0, 0);
}

// ---- fused prep: xd = bf16(x*mask), wb = bf16(W), counts = row histogram,
//      + last-block-done inline scan (two-pass, NO per-thread arrays -> no scratch) ----
__global__ __launch_bounds__(256) void prep_kernel(
    const float* __restrict__ x, const float* __restrict__ m, u16* __restrict__ xd,
    const float* __restrict__ w, u16* __restrict__ wb, const int* __restrict__ rows,
    int* __restrict__ counts, int* __restrict__ done, int* __restrict__ offs) {
  const int stride = gridDim.x * blockDim.x;
  const int tid0 = blockIdx.x * blockDim.x + threadIdx.x;
  for (int i = tid0; i < (NROWS * NFEAT) / 8; i += stride) {
    size_t b = (size_t)i * 2;
    f32x4 a0 = __builtin_nontemporal_load(&((const f32x4*)x)[b]);
    f32x4 a1 = __builtin_nontemporal_load(&((const f32x4*)x)[b + 1]);
    f32x4 m0 = __builtin_nontemporal_load(&((const f32x4*)m)[b]);
    f32x4 m1 = __builtin_nontemporal_load(&((const f32x4*)m)[b + 1]);
    u16x8 o;
    o[0] = f2bf(a0[0] * m0[0]); o[1] = f2bf(a0[1] * m0[1]);
    o[2] = f2bf(a0[2] * m0[2]); o[3] = f2bf(a0[3] * m0[3]);
    o[4] = f2bf(a1[0] * m1[0]); o[5] = f2bf(a1[1] * m1[1]);
    o[6] = f2bf(a1[2] * m1[2]); o[7] = f2bf(a1[3] * m1[3]);
    *(u16x8*)(xd + (size_t)i * 8) = o;
  }
  for (int i = tid0; i < (NFEAT * NFEAT) / 8; i += stride) {
    size_t b = (size_t)i * 2;
    f32x4 a0 = __builtin_nontemporal_load(&((const f32x4*)w)[b]);
    f32x4 a1 = __builtin_nontemporal_load(&((const f32x4*)w)[b + 1]);
    u16x8 o;
    o[0] = f2bf(a0[0]); o[1] = f2bf(a0[1]); o[2] = f2bf(a0[2]); o[3] = f2bf(a0[3]);
    o[4] = f2bf(a1[0]); o[5] = f2bf(a1[1]); o[6] = f2bf(a1[2]); o[7] = f2bf(a1[3]);
    *(u16x8*)(wb + (size_t)i * 8) = o;
  }
  for (int i = tid0; i < NEDGE / 4; i += stride) {
    i32x4 r4 = __builtin_nontemporal_load(&((const i32x4*)rows)[i]);
    atomicAdd(&counts[r4[0]], 1);
    atomicAdd(&counts[r4[1]], 1);
    atomicAdd(&counts[r4[2]], 1);
    atomicAdd(&counts[r4[3]], 1);
  }

  // ---- last-block-done: the final block performs the scan (two-pass, arrayless) ----
  __shared__ int isLast;
  __threadfence();  // release this block's count atomics
  __syncthreads();
  if (threadIdx.x == 0) isLast = (atomicAdd(done, 1) == (int)gridDim.x - 1);
  __syncthreads();
  if (!isLast) return;
  __threadfence();  // acquire: all counts visible

  __shared__ int wpre[5];
  const int t = threadIdx.x;
  const int lane = t & 63, wv = t >> 6;  // 4 waves
  const int beg = t * 196;               // 196 rows/thread, 49 int4 groups
  const int end = (beg + 196 < NROWS) ? beg + 196 : NROWS;
  const int ng4 = (end > beg) ? (end - beg) >> 2 : 0;
  // pass 1: per-thread sum (no storage)
  int s = 0;
  for (int g = 0; g < ng4; ++g) {
    i32x4 c = ((const i32x4*)counts)[(beg >> 2) + g];
    s += c[0] + c[1] + c[2] + c[3];
  }
  int inc = s;
#pragma unroll
  for (int d = 1; d < 64; d <<= 1) {
    int u = __shfl_up(inc, d);
    if (lane >= d) inc += u;
  }
  if (lane == 63) wpre[wv + 1] = inc;
  __syncthreads();
  if (t == 0) {
    wpre[0] = 0;
    for (int i = 1; i <= 4; ++i) wpre[i] += wpre[i - 1];
    offs[NROWS] = NEDGE;
  }
  __syncthreads();
  // pass 2: re-read (L2-hot) and write offs
  int run = wpre[wv] + inc - s;
  for (int g = 0; g < ng4; ++g) {
    i32x4 c = ((const i32x4*)counts)[(beg >> 2) + g];
    i32x4 o;
    o[0] = run; run += c[0];
    o[1] = run; run += c[1];
    o[2] = run; run += c[2];
    o[3] = run; run += c[3];
    ((i32x4*)offs)[(beg >> 2) + g] = o;
  }
}

// ---- hybrid: bid<1564 -> gemm (long pole, starts first); else -> scatter ----
#define GEMM_BLOCKS 1564
__global__ __launch_bounds__(256) void hybrid_kernel(
    const float* __restrict__ vals, const int* __restrict__ rows,
    const int* __restrict__ cols, const int* __restrict__ offs,
    int* __restrict__ cursor, unsigned* __restrict__ svc,
    const u16* __restrict__ xd, const u16* __restrict__ wb,
    unsigned char* __restrict__ hq, float* __restrict__ scaleg) {
  __shared__ __align__(16) u16 lA[128 * 64];  // 16 KB (gemm path only)
  __shared__ float wmax[2][128];
  __shared__ float rinv[128];
  const int tid = threadIdx.x;

  if (blockIdx.x >= GEMM_BLOCKS) {
    // ================= scatter path =================
    int e0 = ((blockIdx.x - GEMM_BLOCKS) * 256 + tid) * 4;
    if (e0 >= NEDGE) return;
    i32x4 r4 = __builtin_nontemporal_load((const i32x4*)(rows + e0));
    i32x4 c4 = __builtin_nontemporal_load((const i32x4*)(cols + e0));
    f32x4 v4 = __builtin_nontemporal_load((const f32x4*)(vals + e0));
#pragma unroll
    for (int j = 0; j < 4; ++j) {
      int p = offs[r4[j]] + atomicAdd(&cursor[r4[j]], 1);
      svc[p] = ((unsigned)c4[j] << 16) | (unsigned)f2bf(v4[j]);
    }
    return;
  }

  // ================= gemm path =================
  const int lane = tid & 63;
  const int wid = tid >> 6;
  const int wm = wid >> 1, wn = wid & 1;
  // bijective XCD swizzle over nwg = 1564 (q=195, r=4)
  const int bx0 = blockIdx.x;
  const int xcd = bx0 & 7, idx = bx0 >> 3;
  const int wg = (xcd < 4 ? xcd * 196 : 784 + (xcd - 4) * 195) + idx;
  const int tm = wg >> 2;
  const int tn = wg & 3;
  const long rowBase = (long)tm * 128;

  f32x4 acc[4][4] = {};

  const int sl8 = lane >> 3;                 // row within 8-row staging call
  const int scol = ((lane & 7) ^ sl8) * 8;   // pre-swizzled global col (u16 units)
  const int rsel = lane & 15, kgrp = (lane >> 4) * 8;
  const u16* bbase = wb + ((long)(tn * 128 + wn * 64 + rsel)) * 512 + kgrp;

  for (int k0 = 0; k0 < 512; k0 += 64) {
    __syncthreads();
#pragma unroll
    for (int c = 0; c < 4; ++c) {
      int rbase = wid * 32 + c * 8;
      long gr = rowBase + rbase + sl8;
      if (gr > NROWS - 1) gr = NROWS - 1;
      gload_lds16(xd + gr * 512 + k0 + scol, lA + rbase * 64);
    }
    // B fragments direct from global (wb is 512 KB, L2-resident)
    short8 b[4][2];
#pragma unroll
    for (int n = 0; n < 4; ++n) {
#pragma unroll
      for (int kk = 0; kk < 2; ++kk)
        b[n][kk] = *(const short8*)(bbase + (long)n * 16 * 512 + k0 + kk * 32);
    }
    __syncthreads();
    short8 a[4][2];
#pragma unroll
    for (int m = 0; m < 4; ++m) {
      int ar = wm * 64 + m * 16 + rsel;
      const u16* base = lA + ar * 64;
      int sw = (ar & 7) << 3;
      a[m][0] = *(const short8*)(base + (kgrp ^ sw));
      a[m][1] = *(const short8*)(base + ((32 + kgrp) ^ sw));
    }
#pragma unroll
    for (int kk = 0; kk < 2; ++kk)
#pragma unroll
      for (int m = 0; m < 4; ++m)
#pragma unroll
        for (int n = 0; n < 4; ++n)
          acc[m][n] = __builtin_amdgcn_mfma_f32_16x16x32_bf16(a[m][kk], b[n][kk], acc[m][n], 0, 0, 0);
  }

  // ---- epilogue: per-row max -> scale, int8 quantize, LDS byte-transpose ----
  const int crow = (lane >> 4) * 4;
  const int ccol = lane & 15;

  float pm[4][4];
#pragma unroll
  for (int m = 0; m < 4; ++m)
#pragma unroll
    for (int r2 = 0; r2 < 4; ++r2) {
      float mx = 0.f;
#pragma unroll
      for (int n = 0; n < 4; ++n) mx = fmaxf(mx, fabsf(lrelu(acc[m][n][r2])));
      pm[m][r2] = mx;
    }
#pragma unroll
  for (int d = 1; d < 16; d <<= 1)
#pragma unroll
    for (int m = 0; m < 4; ++m)
#pragma unroll
      for (int r2 = 0; r2 < 4; ++r2) pm[m][r2] = fmaxf(pm[m][r2], __shfl_xor(pm[m][r2], d));
  if ((lane & 15) == 0) {
#pragma unroll
    for (int m = 0; m < 4; ++m)
#pragma unroll
      for (int r2 = 0; r2 < 4; ++r2) wmax[wn][wm * 64 + m * 16 + crow + r2] = pm[m][r2];
  }
  __syncthreads();  // wmax ready AND all waves done reading lA
  if (tid < 128) {
    float rm = fmaxf(wmax[0][tid], wmax[1][tid]);
    float s = rm > 0.f ? rm * (1.f / 127.f) : 1.f;
    rinv[tid] = rm > 0.f ? 127.f / rm : 0.f;
    long gr = rowBase + tid;
    if (gr < NROWS) scaleg[gr * 4 + tn] = s;
  }
  __syncthreads();

  unsigned char* lT = (unsigned char*)lA;  // 128 x 128 int8 tile (16 KB)
#pragma unroll
  for (int m = 0; m < 4; ++m) {
    int row0 = wm * 64 + m * 16 + crow;
    float ri0 = rinv[row0], ri1 = rinv[row0 + 1], ri2 = rinv[row0 + 2], ri3 = rinv[row0 + 3];
#pragma unroll
    for (int n = 0; n < 4; ++n) {
      int col = wn * 64 + n * 16 + ccol;
      float q0 = rintf(lrelu(acc[m][n][0]) * ri0);
      float q1 = rintf(lrelu(acc[m][n][1]) * ri1);
      float q2 = rintf(lrelu(acc[m][n][2]) * ri2);
      float q3 = rintf(lrelu(acc[m][n][3]) * ri3);
      int i0 = min(127, max(-127, (int)q0));
      int i1 = min(127, max(-127, (int)q1));
      int i2 = min(127, max(-127, (int)q2));
      int i3 = min(127, max(-127, (int)q3));
      unsigned pk = (i0 & 0xff) | ((i1 & 0xff) << 8) | ((i2 & 0xff) << 16) | ((i3 & 0xff) << 24);
#pragma unroll
      for (int r2 = 0; r2 < 4; ++r2) {
        int row = row0 + r2;
        lT[row * 128 + (col ^ ((row & 7) << 4))] = (unsigned char)(pk >> (8 * r2));
      }
    }
  }
  __syncthreads();
  {
    const int row = tid >> 1, seg = tid & 1;
    long gr = rowBase + row;
    if (gr < NROWS) {
      unsigned char* dst = hq + gr * 512 + tn * 128;
#pragma unroll
      for (int j = 0; j < 4; ++j) {
        int s = seg * 4 + j;
        i32x4 vv = *(const i32x4*)(lT + row * 128 + ((s ^ (row & 7)) << 4));
        *(i32x4*)(dst + s * 16) = vv;
      }
    }
  }
}

// ---- aggregate: one WAVE per row, 2 edges/wave (32 lanes each), 16B gathers ----
__global__ __launch_bounds__(256) void aggregate_kernel(const unsigned char* __restrict__ hq,
                                                        const float* __restrict__ scaleg,
                                                        const unsigned* __restrict__ svc,
                                                        const int* __restrict__ offs,
                                                        float* __restrict__ out) {
  const int lane = threadIdx.x & 63;
  const int wid = threadIdx.x >> 6;
  const int r = blockIdx.x * 4 + wid;
  if (r >= NROWS) return;
  const int beg = offs[r], end = offs[r + 1];
  const int half = lane >> 5, sub = lane & 31;
  const int grp = sub >> 3;
  float a[16] = {};
  const unsigned char* hp = hq + sub * 16;
  unsigned cb[4], nb[4];
  const int n = end - beg;
  const int ng = n >> 3;
  if (ng > 0) {
#pragma unroll
    for (int k = 0; k < 4; ++k) cb[k] = svc[beg + 2 * k + half];
  }
  for (int g = 0; g < ng; ++g) {
    if (g + 1 < ng) {
#pragma unroll
      for (int k = 0; k < 4; ++k) nb[k] = svc[beg + (g + 1) * 8 + 2 * k + half];
    }
#pragma unroll
    for (int k = 0; k < 4; ++k) {
      float v = __uint_as_float(cb[k] << 16);
      size_t c = (size_t)(cb[k] >> 16);
      float vs = v * scaleg[c * 4 + grp];
      i32x4 q = *(const i32x4*)(hp + c * 512);
#pragma unroll
      for (int j = 0; j < 4; ++j) {
        unsigned qq = (unsigned)q[j];
        a[4 * j + 0] += vs * (float)(signed char)(qq);
        a[4 * j + 1] += vs * (float)(signed char)(qq >> 8);
        a[4 * j + 2] += vs * (float)(signed char)(qq >> 16);
        a[4 * j + 3] += vs * (float)(signed char)(qq >> 24);
      }
    }
    if (g + 1 < ng) {
#pragma unroll
      for (int k = 0; k < 4; ++k) cb[k] = nb[k];
    }
  }
  int e = beg + ng * 8;
  for (; e + 1 < end; e += 2) {
    unsigned u = svc[e + half];
    float v = __uint_as_float(u << 16);
    size_t c = (size_t)(u >> 16);
    float vs = v * scaleg[c * 4 + grp];
    i32x4 q = *(const i32x4*)(hp + c * 512);
#pragma unroll
    for (int j = 0; j < 4; ++j) {
      unsigned qq = (unsigned)q[j];
      a[4 * j + 0] += vs * (float)(signed char)(qq);
      a[4 * j + 1] += vs * (float)(signed char)(qq >> 8);
      a[4 * j + 2] += vs * (float)(signed char)(qq >> 16);
      a[4 * j + 3] += vs * (float)(signed char)(qq >> 24);
    }
  }
  if (e < end) {
    unsigned u = svc[e];
    float v = __uint_as_float(u << 16);
    size_t c = (size_t)(u >> 16);
    float vs = half ? 0.f : v * scaleg[c * 4 + grp];
    i32x4 q = *(const i32x4*)(hp + c * 512);
#pragma unroll
    for (int j = 0; j < 4; ++j) {
      unsigned qq = (unsigned)q[j];
      a[4 * j + 0] += vs * (float)(signed char)(qq);
      a[4 * j + 1] += vs * (float)(signed char)(qq >> 8);
      a[4 * j + 2] += vs * (float)(signed char)(qq >> 16);
      a[4 * j + 3] += vs * (float)(signed char)(qq >> 24);
    }
  }
#pragma unroll
  for (int j = 0; j < 16; ++j) a[j] += __shfl_xor(a[j], 32);
  if (half == 0) {
    float* op = out + (size_t)r * NFEAT + sub * 16;
#pragma unroll
    for (int j = 0; j < 4; ++j) {
      f32x4 o;
      o[0] = lrelu(a[4 * j + 0]);
      o[1] = lrelu(a[4 * j + 1]);
      o[2] = lrelu(a[4 * j + 2]);
      o[3] = lrelu(a[4 * j + 3]);
      *(f32x4*)(op + 4 * j) = o;
    }
  }
}

extern "C" void kernel_launch(void* const* d_in, const int* in_sizes, int n_in,
                              void* d_out, int out_size, void* d_ws, size_t ws_size,
                              hipStream_t stream) {
  const float* x = (const float*)d_in[0];
  const float* W = (const float*)d_in[1];
  const float* mask = (const float*)d_in[2];
  const float* vals = (const float*)d_in[3];
  const int* rows = (const int*)d_in[4];
  const int* cols = (const int*)d_in[5];
  float* out = (float*)d_out;
  char* ws = (char*)d_ws;

  const size_t o_xd = 0;                       // 51,200,000 (bf16 x*mask)
  const size_t o_hq = o_xd + 51200000;         // 25,600,000 (int8 h)
  const size_t o_wb = o_hq + 25600000;         // 524,288
  const size_t o_scale = o_wb + 524288;        // 800,000 (f32 scale[row][4])
  const size_t o_counts = o_scale + 800000;    // 200,000
  const size_t o_cursor = o_counts + 200000;   // 200,000
  const size_t o_done = o_cursor + 200000;     // 64 (int + pad)
  const size_t o_offs = o_done + 64;           // 200,064
  const size_t o_svc = o_offs + 200064;        // 6,400,000 (u32 packed col|bf16val)

  u16* xd = (u16*)(ws + o_xd);
  unsigned char* hq = (unsigned char*)(ws + o_hq);
  u16* wb = (u16*)(ws + o_wb);
  float* scaleg = (float*)(ws + o_scale);
  int* counts = (int*)(ws + o_counts);
  int* cursor = (int*)(ws + o_cursor);
  int* done = (int*)(ws + o_done);
  int* offs = (int*)(ws + o_offs);
  unsigned* svc = (unsigned*)(ws + o_svc);

  hipMemsetAsync(counts, 0, 400064, stream);  // counts + cursor + done

  prep_kernel<<<2048, 256, 0, stream>>>(x, mask, xd, W, wb, rows, counts, done, offs);
  hybrid_kernel<<<GEMM_BLOCKS + 1563, 256, 0, stream>>>(vals, rows, cols, offs, cursor,
                                                        svc, xd, wb, hq, scaleg);
  aggregate_kernel<<<12500, 256, 0, stream>>>(hq, scaleg, svc, offs, out);
}

// Round 20
// 376.588 us; speedup vs baseline: 1.9214x; 1.9163x over previous
//
#include <hip/hip_runtime.h>

#define NROWS 50000
#define NFEAT 512
#define NEDGE 1600000
#define SLOPE 0.01f

typedef unsigned short u16;
typedef __attribute__((ext_vector_type(8))) short short8;
typedef __attribute__((ext_vector_type(4))) float f32x4;
typedef __attribute__((ext_vector_type(4))) int i32x4;
typedef __attribute__((ext_vector_type(8))) unsigned short u16x8;

__device__ __forceinline__ u16 f2bf(float f) {
  unsigned u = __float_as_uint(f);
  u += 0x7fffu + ((u >> 16) & 1u);
  return (u16)(u >> 16);
}
__device__ __forceinline__ float lrelu(float v) { return v >= 0.f ? v : SLOPE * v; }

__device__ __forceinline__ void gload_lds16(const u16* g, u16* l) {
  __builtin_amdgcn_global_load_lds((const __attribute__((address_space(1))) void*)g,
                                   (__attribute__((address_space(3))) void*)l, 16, 0, 0);
}

// ---- fused prep: xd = bf16(x*mask), wb = bf16(W), counts = row histogram ----
__global__ void prep_kernel(const float* __restrict__ x, const float* __restrict__ m,
                            u16* __restrict__ xd, const float* __restrict__ w,
                            u16* __restrict__ wb, const int* __restrict__ rows,
                            int* __restrict__ counts) {
  const int stride = gridDim.x * blockDim.x;
  const int tid0 = blockIdx.x * blockDim.x + threadIdx.x;
  for (int i = tid0; i < (NROWS * NFEAT) / 8; i += stride) {
    size_t b = (size_t)i * 2;
    f32x4 a0 = __builtin_nontemporal_load(&((const f32x4*)x)[b]);
    f32x4 a1 = __builtin_nontemporal_load(&((const f32x4*)x)[b + 1]);
    f32x4 m0 = __builtin_nontemporal_load(&((const f32x4*)m)[b]);
    f32x4 m1 = __builtin_nontemporal_load(&((const f32x4*)m)[b + 1]);
    u16x8 o;
    o[0] = f2bf(a0[0] * m0[0]); o[1] = f2bf(a0[1] * m0[1]);
    o[2] = f2bf(a0[2] * m0[2]); o[3] = f2bf(a0[3] * m0[3]);
    o[4] = f2bf(a1[0] * m1[0]); o[5] = f2bf(a1[1] * m1[1]);
    o[6] = f2bf(a1[2] * m1[2]); o[7] = f2bf(a1[3] * m1[3]);
    *(u16x8*)(xd + (size_t)i * 8) = o;
  }
  for (int i = tid0; i < (NFEAT * NFEAT) / 8; i += stride) {
    size_t b = (size_t)i * 2;
    f32x4 a0 = __builtin_nontemporal_load(&((const f32x4*)w)[b]);
    f32x4 a1 = __builtin_nontemporal_load(&((const f32x4*)w)[b + 1]);
    u16x8 o;
    o[0] = f2bf(a0[0]); o[1] = f2bf(a0[1]); o[2] = f2bf(a0[2]); o[3] = f2bf(a0[3]);
    o[4] = f2bf(a1[0]); o[5] = f2bf(a1[1]); o[6] = f2bf(a1[2]); o[7] = f2bf(a1[3]);
    *(u16x8*)(wb + (size_t)i * 8) = o;
  }
  for (int i = tid0; i < NEDGE / 4; i += stride) {
    i32x4 r4 = __builtin_nontemporal_load(&((const i32x4*)rows)[i]);
    atomicAdd(&counts[r4[0]], 1);
    atomicAdd(&counts[r4[1]], 1);
    atomicAdd(&counts[r4[2]], 1);
    atomicAdd(&counts[r4[3]], 1);
  }
}

// ---- scan: CH=64 per thread, int4 loads/stores, shfl wave-scan ----
__global__ void scan_kernel(const int* __restrict__ counts, int* __restrict__ offs) {
  __shared__ int wpre[17];
  const int t = threadIdx.x;            // 1024 threads
  const int lane = t & 63, w = t >> 6;  // 16 waves
  const int beg = t * 64;
  i32x4 c4[16];
  int s = 0;
  if (beg < NROWS) {
#pragma unroll
    for (int g = 0; g < 16; ++g) {
      int idx = beg + g * 4;
      if (idx < NROWS) {
        c4[g] = ((const i32x4*)counts)[idx >> 2];
        s += c4[g][0] + c4[g][1] + c4[g][2] + c4[g][3];
      }
    }
  }
  int inc = s;
#pragma unroll
  for (int d = 1; d < 64; d <<= 1) {
    int u = __shfl_up(inc, d);
    if (lane >= d) inc += u;
  }
  if (lane == 63) wpre[w + 1] = inc;
  __syncthreads();
  if (t == 0) {
    wpre[0] = 0;
    for (int i = 1; i <= 16; ++i) wpre[i] += wpre[i - 1];
    offs[NROWS] = wpre[16];
  }
  __syncthreads();
  int run = wpre[w] + inc - s;
  if (beg < NROWS) {
#pragma unroll
    for (int g = 0; g < 16; ++g) {
      int idx = beg + g * 4;
      if (idx < NROWS) {
        i32x4 o;
        o[0] = run; run += c4[g][0];
        o[1] = run; run += c4[g][1];
        o[2] = run; run += c4[g][2];
        o[3] = run; run += c4[g][3];
        ((i32x4*)offs)[idx >> 2] = o;
      }
    }
  }
}

// ---- hybrid: bid<1564 -> gemm (long pole, starts first); else -> scatter ----
#define GEMM_BLOCKS 1564
__global__ __launch_bounds__(256) void hybrid_kernel(
    const float* __restrict__ vals, const int* __restrict__ rows,
    const int* __restrict__ cols, const int* __restrict__ offs,
    int* __restrict__ cursor, unsigned* __restrict__ svc,
    const u16* __restrict__ xd, const u16* __restrict__ wb,
    unsigned char* __restrict__ hq, float* __restrict__ scaleg) {
  __shared__ __align__(16) u16 lA[128 * 64];  // 16 KB (gemm path only)
  __shared__ float wmax[2][128];
  __shared__ float rinv[128];
  const int tid = threadIdx.x;

  if (blockIdx.x >= GEMM_BLOCKS) {
    // ================= scatter path =================
    int e0 = ((blockIdx.x - GEMM_BLOCKS) * 256 + tid) * 4;
    if (e0 >= NEDGE) return;
    i32x4 r4 = __builtin_nontemporal_load((const i32x4*)(rows + e0));
    i32x4 c4 = __builtin_nontemporal_load((const i32x4*)(cols + e0));
    f32x4 v4 = __builtin_nontemporal_load((const f32x4*)(vals + e0));
#pragma unroll
    for (int j = 0; j < 4; ++j) {
      int p = offs[r4[j]] + atomicAdd(&cursor[r4[j]], 1);
      svc[p] = ((unsigned)c4[j] << 16) | (unsigned)f2bf(v4[j]);
    }
    return;
  }

  // ================= gemm path =================
  const int lane = tid & 63;
  const int wid = tid >> 6;
  const int wm = wid >> 1, wn = wid & 1;
  // bijective XCD swizzle over nwg = 1564 (q=195, r=4)
  const int bx0 = blockIdx.x;
  const int xcd = bx0 & 7, idx = bx0 >> 3;
  const int wg = (xcd < 4 ? xcd * 196 : 784 + (xcd - 4) * 195) + idx;
  const int tm = wg >> 2;
  const int tn = wg & 3;
  const long rowBase = (long)tm * 128;

  f32x4 acc[4][4] = {};

  const int sl8 = lane >> 3;                 // row within 8-row staging call
  const int scol = ((lane & 7) ^ sl8) * 8;   // pre-swizzled global col (u16 units)
  const int rsel = lane & 15, kgrp = (lane >> 4) * 8;
  const u16* bbase = wb + ((long)(tn * 128 + wn * 64 + rsel)) * 512 + kgrp;

  for (int k0 = 0; k0 < 512; k0 += 64) {
    __syncthreads();
#pragma unroll
    for (int c = 0; c < 4; ++c) {
      int rbase = wid * 32 + c * 8;
      long gr = rowBase + rbase + sl8;
      if (gr > NROWS - 1) gr = NROWS - 1;
      gload_lds16(xd + gr * 512 + k0 + scol, lA + rbase * 64);
    }
    // B fragments direct from global (wb is 512 KB, L2-resident)
    short8 b[4][2];
#pragma unroll
    for (int n = 0; n < 4; ++n) {
#pragma unroll
      for (int kk = 0; kk < 2; ++kk)
        b[n][kk] = *(const short8*)(bbase + (long)n * 16 * 512 + k0 + kk * 32);
    }
    __syncthreads();
    short8 a[4][2];
#pragma unroll
    for (int m = 0; m < 4; ++m) {
      int ar = wm * 64 + m * 16 + rsel;
      const u16* base = lA + ar * 64;
      int sw = (ar & 7) << 3;
      a[m][0] = *(const short8*)(base + (kgrp ^ sw));
      a[m][1] = *(const short8*)(base + ((32 + kgrp) ^ sw));
    }
#pragma unroll
    for (int kk = 0; kk < 2; ++kk)
#pragma unroll
      for (int m = 0; m < 4; ++m)
#pragma unroll
        for (int n = 0; n < 4; ++n)
          acc[m][n] = __builtin_amdgcn_mfma_f32_16x16x32_bf16(a[m][kk], b[n][kk], acc[m][n], 0, 0, 0);
  }

  // ---- epilogue: per-row max -> scale, int8 quantize, LDS byte-transpose ----
  const int crow = (lane >> 4) * 4;
  const int ccol = lane & 15;

  float pm[4][4];
#pragma unroll
  for (int m = 0; m < 4; ++m)
#pragma unroll
    for (int r2 = 0; r2 < 4; ++r2) {
      float mx = 0.f;
#pragma unroll
      for (int n = 0; n < 4; ++n) mx = fmaxf(mx, fabsf(lrelu(acc[m][n][r2])));
      pm[m][r2] = mx;
    }
#pragma unroll
  for (int d = 1; d < 16; d <<= 1)
#pragma unroll
    for (int m = 0; m < 4; ++m)
#pragma unroll
      for (int r2 = 0; r2 < 4; ++r2) pm[m][r2] = fmaxf(pm[m][r2], __shfl_xor(pm[m][r2], d));
  if ((lane & 15) == 0) {
#pragma unroll
    for (int m = 0; m < 4; ++m)
#pragma unroll
      for (int r2 = 0; r2 < 4; ++r2) wmax[wn][wm * 64 + m * 16 + crow + r2] = pm[m][r2];
  }
  __syncthreads();  // wmax ready AND all waves done reading lA
  if (tid < 128) {
    float rm = fmaxf(wmax[0][tid], wmax[1][tid]);
    float s = rm > 0.f ? rm * (1.f / 127.f) : 1.f;
    rinv[tid] = rm > 0.f ? 127.f / rm : 0.f;
    long gr = rowBase + tid;
    if (gr < NROWS) scaleg[gr * 4 + tn] = s;
  }
  __syncthreads();

  unsigned char* lT = (unsigned char*)lA;  // 128 x 128 int8 tile (16 KB)
#pragma unroll
  for (int m = 0; m < 4; ++m) {
    int row0 = wm * 64 + m * 16 + crow;
    float ri0 = rinv[row0], ri1 = rinv[row0 + 1], ri2 = rinv[row0 + 2], ri3 = rinv[row0 + 3];
#pragma unroll
    for (int n = 0; n < 4; ++n) {
      int col = wn * 64 + n * 16 + ccol;
      float q0 = rintf(lrelu(acc[m][n][0]) * ri0);
      float q1 = rintf(lrelu(acc[m][n][1]) * ri1);
      float q2 = rintf(lrelu(acc[m][n][2]) * ri2);
      float q3 = rintf(lrelu(acc[m][n][3]) * ri3);
      int i0 = min(127, max(-127, (int)q0));
      int i1 = min(127, max(-127, (int)q1));
      int i2 = min(127, max(-127, (int)q2));
      int i3 = min(127, max(-127, (int)q3));
      unsigned pk = (i0 & 0xff) | ((i1 & 0xff) << 8) | ((i2 & 0xff) << 16) | ((i3 & 0xff) << 24);
#pragma unroll
      for (int r2 = 0; r2 < 4; ++r2) {
        int row = row0 + r2;
        lT[row * 128 + (col ^ ((row & 7) << 4))] = (unsigned char)(pk >> (8 * r2));
      }
    }
  }
  __syncthreads();
  {
    const int row = tid >> 1, seg = tid & 1;
    long gr = rowBase + row;
    if (gr < NROWS) {
      unsigned char* dst = hq + gr * 512 + tn * 128;
#pragma unroll
      for (int j = 0; j < 4; ++j) {
        int s = seg * 4 + j;
        i32x4 vv = *(const i32x4*)(lT + row * 128 + ((s ^ (row & 7)) << 4));
        *(i32x4*)(dst + s * 16) = vv;
      }
    }
  }
}

// ---- aggregate: one WAVE per row, 2 edges/wave (32 lanes each), 16B gathers ----
__global__ __launch_bounds__(256) void aggregate_kernel(const unsigned char* __restrict__ hq,
                                                        const float* __restrict__ scaleg,
                                                        const unsigned* __restrict__ svc,
                                                        const int* __restrict__ offs,
                                                        float* __restrict__ out) {
  const int lane = threadIdx.x & 63;
  const int wid = threadIdx.x >> 6;
  const int r = blockIdx.x * 4 + wid;
  if (r >= NROWS) return;
  const int beg = offs[r], end = offs[r + 1];
  const int half = lane >> 5, sub = lane & 31;
  const int grp = sub >> 3;
  float a[16] = {};
  const unsigned char* hp = hq + sub * 16;
  unsigned cb[4], nb[4];
  const int n = end - beg;
  const int ng = n >> 3;
  if (ng > 0) {
#pragma unroll
    for (int k = 0; k < 4; ++k) cb[k] = svc[beg + 2 * k + half];
  }
  for (int g = 0; g < ng; ++g) {
    if (g + 1 < ng) {
#pragma unroll
      for (int k = 0; k < 4; ++k) nb[k] = svc[beg + (g + 1) * 8 + 2 * k + half];
    }
#pragma unroll
    for (int k = 0; k < 4; ++k) {
      float v = __uint_as_float(cb[k] << 16);
      size_t c = (size_t)(cb[k] >> 16);
      float vs = v * scaleg[c * 4 + grp];
      i32x4 q = *(const i32x4*)(hp + c * 512);
#pragma unroll
      for (int j = 0; j < 4; ++j) {
        unsigned qq = (unsigned)q[j];
        a[4 * j + 0] += vs * (float)(signed char)(qq);
        a[4 * j + 1] += vs * (float)(signed char)(qq >> 8);
        a[4 * j + 2] += vs * (float)(signed char)(qq >> 16);
        a[4 * j + 3] += vs * (float)(signed char)(qq >> 24);
      }
    }
    if (g + 1 < ng) {
#pragma unroll
      for (int k = 0; k < 4; ++k) cb[k] = nb[k];
    }
  }
  int e = beg + ng * 8;
  for (; e + 1 < end; e += 2) {
    unsigned u = svc[e + half];
    float v = __uint_as_float(u << 16);
    size_t c = (size_t)(u >> 16);
    float vs = v * scaleg[c * 4 + grp];
    i32x4 q = *(const i32x4*)(hp + c * 512);
#pragma unroll
    for (int j = 0; j < 4; ++j) {
      unsigned qq = (unsigned)q[j];
      a[4 * j + 0] += vs * (float)(signed char)(qq);
      a[4 * j + 1] += vs * (float)(signed char)(qq >> 8);
      a[4 * j + 2] += vs * (float)(signed char)(qq >> 16);
      a[4 * j + 3] += vs * (float)(signed char)(qq >> 24);
    }
  }
  if (e < end) {
    unsigned u = svc[e];
    float v = __uint_as_float(u << 16);
    size_t c = (size_t)(u >> 16);
    float vs = half ? 0.f : v * scaleg[c * 4 + grp];
    i32x4 q = *(const i32x4*)(hp + c * 512);
#pragma unroll
    for (int j = 0; j < 4; ++j) {
      unsigned qq = (unsigned)q[j];
      a[4 * j + 0] += vs * (float)(signed char)(qq);
      a[4 * j + 1] += vs * (float)(signed char)(qq >> 8);
      a[4 * j + 2] += vs * (float)(signed char)(qq >> 16);
      a[4 * j + 3] += vs * (float)(signed char)(qq >> 24);
    }
  }
#pragma unroll
  for (int j = 0; j < 16; ++j) a[j] += __shfl_xor(a[j], 32);
  if (half == 0) {
    float* op = out + (size_t)r * NFEAT + sub * 16;
#pragma unroll
    for (int j = 0; j < 4; ++j) {
      f32x4 o;
      o[0] = lrelu(a[4 * j + 0]);
      o[1] = lrelu(a[4 * j + 1]);
      o[2] = lrelu(a[4 * j + 2]);
      o[3] = lrelu(a[4 * j + 3]);
      *(f32x4*)(op + 4 * j) = o;
    }
  }
}

extern "C" void kernel_launch(void* const* d_in, const int* in_sizes, int n_in,
                              void* d_out, int out_size, void* d_ws, size_t ws_size,
                              hipStream_t stream) {
  const float* x = (const float*)d_in[0];
  const float* W = (const float*)d_in[1];
  const float* mask = (const float*)d_in[2];
  const float* vals = (const float*)d_in[3];
  const int* rows = (const int*)d_in[4];
  const int* cols = (const int*)d_in[5];
  float* out = (float*)d_out;
  char* ws = (char*)d_ws;

  const size_t o_xd = 0;                       // 51,200,000 (bf16 x*mask)
  const size_t o_hq = o_xd + 51200000;         // 25,600,000 (int8 h)
  const size_t o_wb = o_hq + 25600000;         // 524,288
  const size_t o_scale = o_wb + 524288;        // 800,000 (f32 scale[row][4])
  const size_t o_counts = o_scale + 800000;    // 200,000
  const size_t o_cursor = o_counts + 200000;   // 200,000
  const size_t o_offs = o_cursor + 200000;     // 200,064
  const size_t o_svc = o_offs + 200064;        // 6,400,000 (u32 packed col|bf16val)

  u16* xd = (u16*)(ws + o_xd);
  unsigned char* hq = (unsigned char*)(ws + o_hq);
  u16* wb = (u16*)(ws + o_wb);
  float* scaleg = (float*)(ws + o_scale);
  int* counts = (int*)(ws + o_counts);
  int* cursor = (int*)(ws + o_cursor);
  int* offs = (int*)(ws + o_offs);
  unsigned* svc = (unsigned*)(ws + o_svc);

  hipMemsetAsync(counts, 0, 400000, stream);  // counts + cursor

  prep_kernel<<<2048, 256, 0, stream>>>(x, mask, xd, W, wb, rows, counts);
  scan_kernel<<<1, 1024, 0, stream>>>(counts, offs);
  hybrid_kernel<<<GEMM_BLOCKS + 1563, 256, 0, stream>>>(vals, rows, cols, offs, cursor,
                                                        svc, xd, wb, hq, scaleg);
  aggregate_kernel<<<12500, 256, 0, stream>>>(hq, scaleg, svc, offs, out);
}